// Round 5
// baseline (110.042 us; speedup 1.0000x reference)
//
#include <hip/hip_runtime.h>
#include <math.h>

#define BB 2
#define LL 2048
#define DM 512
#define DS 16
#define DTR 32
#define KK 64          // DTR + 2*DS
#define NC 128         // chunks
#define CL 16          // LL / NC
#define NROWS (BB * LL)
#define CHAINS (BB * DM * DS)   // 16384

// ws layout (floats) — ~43 MB total, ws is ~268 MB
#define OFF_WXT  0                        // 512*64    = 32768
#define OFF_WDTT (OFF_WXT + DM * KK)      // 32*512    = 16384
#define OFF_XZ   (OFF_WDTT + DTR * DM)    // 4096*64   = 262144
#define OFF_DTT  (OFF_XZ + NROWS * KK)    // 4096*512  = 2097152  dtT[b][c][d][CL]
#define OFF_UT   (OFF_DTT + NROWS * DM)   // 4096*512  = 2097152  uT = dt*x, same layout
#define OFF_P    (OFF_UT + NROWS * DM)    // 128*16384 = 2097152
#define OFF_H    (OFF_P + NC * CHAINS)    // 128*16384 = 2097152
#define OFF_C    (OFF_H + NC * CHAINS)    // 128*16384 = 2097152

__global__ __launch_bounds__(256) void k_prep(const float* __restrict__ W_x,
                                              const float* __restrict__ W_dt,
                                              float* __restrict__ WxT,
                                              float* __restrict__ WdtT) {
  int i = blockIdx.x * 256 + threadIdx.x;
  if (i < DM * KK) {                 // WxT[d][k] = W_x[k][d]
    int d = i / KK, k = i % KK;
    WxT[i] = W_x[k * DM + d];
  }
  int j = i - DM * KK;
  if (j >= 0 && j < DTR * DM) {      // WdtT[r][d] = W_dt[d][r]
    int r = j / DM, d = j % DM;
    WdtT[j] = W_dt[d * DTR + r];
  }
}

// xz[row][k] = sum_d x[row][d] * W_x[k][d]
// 512-thread block: 8 waves = 4 row-pairs x 2 d-halves; LDS reduce across halves.
__global__ __launch_bounds__(512) void k_xz(const float* __restrict__ x,
                                            const float* __restrict__ WxT,
                                            float* __restrict__ xz) {
  __shared__ float red[4][2][64];
  int k = threadIdx.x & 63;
  int wv = threadIdx.x >> 6;   // 0..7
  int rp = wv & 3;             // row pair
  int dh = wv >> 2;            // d half
  int row0 = blockIdx.x * 8 + rp * 2;
  const float* xr0 = x + (size_t)row0 * DM + dh * (DM / 2);
  const float* xr1 = xr0 + DM;
  const float* Wp = WxT + (size_t)dh * (DM / 2) * KK;
  float acc0 = 0.f, acc1 = 0.f;
  for (int d = 0; d < DM / 2; d += 8) {
    float4 u0 = *(const float4*)(xr0 + d);
    float4 u1 = *(const float4*)(xr0 + d + 4);
    float4 v0 = *(const float4*)(xr1 + d);
    float4 v1 = *(const float4*)(xr1 + d + 4);
    float w0 = Wp[(d + 0) * KK + k];
    float w1 = Wp[(d + 1) * KK + k];
    float w2 = Wp[(d + 2) * KK + k];
    float w3 = Wp[(d + 3) * KK + k];
    float w4 = Wp[(d + 4) * KK + k];
    float w5 = Wp[(d + 5) * KK + k];
    float w6 = Wp[(d + 6) * KK + k];
    float w7 = Wp[(d + 7) * KK + k];
    acc0 = fmaf(u0.x, w0, acc0); acc1 = fmaf(v0.x, w0, acc1);
    acc0 = fmaf(u0.y, w1, acc0); acc1 = fmaf(v0.y, w1, acc1);
    acc0 = fmaf(u0.z, w2, acc0); acc1 = fmaf(v0.z, w2, acc1);
    acc0 = fmaf(u0.w, w3, acc0); acc1 = fmaf(v0.w, w3, acc1);
    acc0 = fmaf(u1.x, w4, acc0); acc1 = fmaf(v1.x, w4, acc1);
    acc0 = fmaf(u1.y, w5, acc0); acc1 = fmaf(v1.y, w5, acc1);
    acc0 = fmaf(u1.z, w6, acc0); acc1 = fmaf(v1.z, w6, acc1);
    acc0 = fmaf(u1.w, w7, acc0); acc1 = fmaf(v1.w, w7, acc1);
  }
  if (dh == 1) {
    red[rp][0][k] = acc0;
    red[rp][1][k] = acc1;
  }
  __syncthreads();
  if (dh == 0) {
    acc0 += red[rp][0][k];
    acc1 += red[rp][1][k];
    xz[(size_t)row0 * KK + k] = acc0;
    xz[(size_t)(row0 + 1) * KK + k] = acc1;
  }
}

// dt = clip(softplus(dt_raw @ W_dt^T + b_dt)); writes dtT and uT=dt*x in
// chunk-major layout [b][c][d][CL] so scans load contiguously along l.
__global__ __launch_bounds__(256) void k_dt(const float* __restrict__ xz,
                                            const float* __restrict__ WdtT,
                                            const float* __restrict__ b_dt,
                                            const float* __restrict__ x,
                                            float* __restrict__ dtT,
                                            float* __restrict__ uT) {
  int d = (blockIdx.x & 1) * 256 + threadIdx.x;
  int row0 = (blockIdx.x >> 1) * 8;
  int b = row0 >> 11;          // / LL
  int l0 = row0 & (LL - 1);
  int c = l0 >> 4;             // / CL
  int o = l0 & (CL - 1);       // 0 or 8
  float acc[8] = {0, 0, 0, 0, 0, 0, 0, 0};
  for (int r = 0; r < DTR; ++r) {
    float w = WdtT[r * DM + d];
#pragma unroll
    for (int i = 0; i < 8; ++i)
      acc[i] += xz[(row0 + i) * KK + r] * w;
  }
  float bd = b_dt[d];
  float dtv[8], uv[8];
#pragma unroll
  for (int i = 0; i < 8; ++i) {
    float v = acc[i] + bd;
    float sp = v > 15.f ? v : __logf(1.f + __expf(v));
    sp = fminf(fmaxf(sp, 1e-4f), 10.f);
    dtv[i] = sp;
    uv[i] = sp * x[(size_t)(row0 + i) * DM + d];
  }
  size_t base = ((size_t)(b * NC + c) * DM + d) * CL + o;
  *(float4*)(dtT + base)     = make_float4(dtv[0], dtv[1], dtv[2], dtv[3]);
  *(float4*)(dtT + base + 4) = make_float4(dtv[4], dtv[5], dtv[6], dtv[7]);
  *(float4*)(uT + base)      = make_float4(uv[0], uv[1], uv[2], uv[3]);
  *(float4*)(uT + base + 4)  = make_float4(uv[4], uv[5], uv[6], uv[7]);
}

#define LOAD16(arr, ptr)                                                    \
  {                                                                         \
    float4 q0 = *(const float4*)(ptr);                                      \
    float4 q1 = *(const float4*)((ptr) + 4);                                \
    float4 q2 = *(const float4*)((ptr) + 8);                                \
    float4 q3 = *(const float4*)((ptr) + 12);                               \
    arr[0] = q0.x; arr[1] = q0.y; arr[2] = q0.z; arr[3] = q0.w;             \
    arr[4] = q1.x; arr[5] = q1.y; arr[6] = q1.z; arr[7] = q1.w;             \
    arr[8] = q2.x; arr[9] = q2.y; arr[10] = q2.z; arr[11] = q2.w;           \
    arr[12] = q3.x; arr[13] = q3.y; arr[14] = q3.z; arr[15] = q3.w;         \
  }

// Pass 1: per-chunk (prod A_bar, local h). 4 states/thread, dt/u in registers.
__global__ __launch_bounds__(256) void k_scan1(const float* __restrict__ xz,
                                               const float* __restrict__ dtT,
                                               const float* __restrict__ uT,
                                               const float* __restrict__ A_log,
                                               float* __restrict__ Pb,
                                               float* __restrict__ Hb) {
  int c = blockIdx.x;
  int b = blockIdx.y >> 3;
  int dblk = blockIdx.y & 7;
  int tid = threadIdx.x;
  int s4 = tid & 3, dloc = tid >> 2;
  int d = dblk * 64 + dloc;

  float4 al = *(const float4*)(A_log + d * DS + s4 * 4);
  float A0 = fminf(-__expf(al.x), -1e-4f);
  float A1 = fminf(-__expf(al.y), -1e-4f);
  float A2 = fminf(-__expf(al.z), -1e-4f);
  float A3 = fminf(-__expf(al.w), -1e-4f);

  size_t tb = ((size_t)(b * NC + c) * DM + d) * CL;
  float dtv[16], uv[16];
  LOAD16(dtv, dtT + tb);
  LOAD16(uv, uT + tb);

  float P0 = 1.f, P1 = 1.f, P2 = 1.f, P3 = 1.f;
  float h0 = 0.f, h1 = 0.f, h2 = 0.f, h3 = 0.f;
  const float* B_p = xz + ((size_t)b * LL + c * CL) * KK + DTR + s4 * 4;
#pragma unroll
  for (int l = 0; l < CL; ++l) {
    float4 Bv = *(const float4*)(B_p + (size_t)l * KK);
    float a0 = fminf(__expf(dtv[l] * A0), 1.f);
    float a1 = fminf(__expf(dtv[l] * A1), 1.f);
    float a2 = fminf(__expf(dtv[l] * A2), 1.f);
    float a3 = fminf(__expf(dtv[l] * A3), 1.f);
    h0 = fmaf(a0, h0, uv[l] * Bv.x); P0 *= a0;
    h1 = fmaf(a1, h1, uv[l] * Bv.y); P1 *= a1;
    h2 = fmaf(a2, h2, uv[l] * Bv.z); P2 *= a2;
    h3 = fmaf(a3, h3, uv[l] * Bv.w); P3 *= a3;
  }
  int chain0 = (b * DM + d) * DS + s4 * 4;
  *(float4*)(Pb + (size_t)c * CHAINS + chain0) = make_float4(P0, P1, P2, P3);
  *(float4*)(Hb + (size_t)c * CHAINS + chain0) = make_float4(h0, h1, h2, h3);
}

// Carry scan over chunks. PURE: reads Pb/Hb, writes Cb.
__global__ __launch_bounds__(256) void k_mid(const float* __restrict__ Pb,
                                             const float* __restrict__ Hb,
                                             float* __restrict__ Cb) {
  int chain = blockIdx.x * 256 + threadIdx.x;
  float h = 0.f;
#pragma unroll 16
  for (int c = 0; c < NC; ++c) {
    float Pv = Pb[(size_t)c * CHAINS + chain];
    float Hv = Hb[(size_t)c * CHAINS + chain];
    Cb[(size_t)c * CHAINS + chain] = h;
    h = fmaf(Pv, h, Hv);
  }
}

// Pass 2: carry-in + local scan + y output.
__global__ __launch_bounds__(256) void k_scan2(const float* __restrict__ x,
                                               const float* __restrict__ xz,
                                               const float* __restrict__ dtT,
                                               const float* __restrict__ uT,
                                               const float* __restrict__ A_log,
                                               const float* __restrict__ Dv,
                                               const float* __restrict__ Cb,
                                               float* __restrict__ y) {
  int c = blockIdx.x;
  int b = blockIdx.y >> 3;
  int dblk = blockIdx.y & 7;
  int tid = threadIdx.x;
  int s4 = tid & 3, dloc = tid >> 2;
  int d = dblk * 64 + dloc;

  float4 al = *(const float4*)(A_log + d * DS + s4 * 4);
  float A0 = fminf(-__expf(al.x), -1e-4f);
  float A1 = fminf(-__expf(al.y), -1e-4f);
  float A2 = fminf(-__expf(al.z), -1e-4f);
  float A3 = fminf(-__expf(al.w), -1e-4f);
  float Dd = Dv[d];

  int chain0 = (b * DM + d) * DS + s4 * 4;
  float4 hc = *(const float4*)(Cb + (size_t)c * CHAINS + chain0);
  float h0 = hc.x, h1 = hc.y, h2 = hc.z, h3 = hc.w;

  size_t tb = ((size_t)(b * NC + c) * DM + d) * CL;
  float dtv[16], uv[16];
  LOAD16(dtv, dtT + tb);
  LOAD16(uv, uT + tb);

  const float* B_p = xz + ((size_t)b * LL + c * CL) * KK + DTR + s4 * 4;
  const float* C_p = B_p + DS;
  const float* x_p = x + ((size_t)b * LL + c * CL) * DM + d;
  float* y_p = y + ((size_t)b * LL + c * CL) * DM + d;
#pragma unroll
  for (int l = 0; l < CL; ++l) {
    float4 Bv = *(const float4*)(B_p + (size_t)l * KK);
    float4 Cv = *(const float4*)(C_p + (size_t)l * KK);
    float a0 = fminf(__expf(dtv[l] * A0), 1.f);
    float a1 = fminf(__expf(dtv[l] * A1), 1.f);
    float a2 = fminf(__expf(dtv[l] * A2), 1.f);
    float a3 = fminf(__expf(dtv[l] * A3), 1.f);
    h0 = fmaf(a0, h0, uv[l] * Bv.x);
    h1 = fmaf(a1, h1, uv[l] * Bv.y);
    h2 = fmaf(a2, h2, uv[l] * Bv.z);
    h3 = fmaf(a3, h3, uv[l] * Bv.w);
    float p = h0 * Cv.x;
    p = fmaf(h1, Cv.y, p);
    p = fmaf(h2, Cv.z, p);
    p = fmaf(h3, Cv.w, p);
    p += __shfl_xor(p, 1);
    p += __shfl_xor(p, 2);
    if (s4 == 0) {
      float xv = x_p[(size_t)l * DM];
      y_p[(size_t)l * DM] = fmaf(xv, Dd, p);
    }
  }
}

extern "C" void kernel_launch(void* const* d_in, const int* in_sizes, int n_in,
                              void* d_out, int out_size, void* d_ws, size_t ws_size,
                              hipStream_t stream) {
  const float* x     = (const float*)d_in[0];
  const float* W_x   = (const float*)d_in[1];
  const float* W_dt  = (const float*)d_in[2];
  const float* b_dt  = (const float*)d_in[3];
  const float* A_log = (const float*)d_in[4];
  const float* Dv    = (const float*)d_in[5];
  float* y = (float*)d_out;

  float* ws   = (float*)d_ws;
  float* WxT  = ws + OFF_WXT;
  float* WdtT = ws + OFF_WDTT;
  float* xz   = ws + OFF_XZ;
  float* dtT  = ws + OFF_DTT;
  float* uT   = ws + OFF_UT;
  float* Pb   = ws + OFF_P;
  float* Hb   = ws + OFF_H;
  float* Cb   = ws + OFF_C;

  k_prep<<<192, 256, 0, stream>>>(W_x, W_dt, WxT, WdtT);
  k_xz<<<NROWS / 8, 512, 0, stream>>>(x, WxT, xz);
  k_dt<<<(NROWS / 8) * 2, 256, 0, stream>>>(xz, WdtT, b_dt, x, dtT, uT);
  dim3 g(NC, BB * (DM / 64));
  k_scan1<<<g, 256, 0, stream>>>(xz, dtT, uT, A_log, Pb, Hb);
  k_mid<<<CHAINS / 256, 256, 0, stream>>>(Pb, Hb, Cb);
  k_scan2<<<g, 256, 0, stream>>>(x, xz, dtT, uT, A_log, Dv, Cb, y);
}

// Round 6
// 109.177 us; speedup vs baseline: 1.0079x; 1.0079x over previous
//
#include <hip/hip_runtime.h>
#include <math.h>

#define BB 2
#define LL 2048
#define DM 512
#define DS 16
#define DTR 32
#define KK 64          // DTR + 2*DS
#define NC 128         // chunks
#define CL 16          // LL / NC
#define NROWS (BB * LL)
#define CHAINS (BB * DM * DS)   // 16384

// ws layout (floats) — ~35 MB, ws is ~268 MB
#define OFF_WXT  0                        // 512*64    = 32768
#define OFF_WDTT (OFF_WXT + DM * KK)      // 32*512    = 16384
#define OFF_XZ   (OFF_WDTT + DTR * DM)    // 4096*64   = 262144
#define OFF_DT   (OFF_XZ + NROWS * KK)    // 4096*512  = 2097152
#define OFF_P    (OFF_DT + NROWS * DM)    // 128*16384 = 2097152
#define OFF_H    (OFF_P + NC * CHAINS)    // 128*16384 = 2097152
#define OFF_C    (OFF_H + NC * CHAINS)    // 128*16384 = 2097152

__global__ __launch_bounds__(256) void k_prep(const float* __restrict__ W_x,
                                              const float* __restrict__ W_dt,
                                              float* __restrict__ WxT,
                                              float* __restrict__ WdtT) {
  int i = blockIdx.x * 256 + threadIdx.x;
  if (i < DM * KK) {                 // WxT[d][k] = W_x[k][d]
    int d = i / KK, k = i % KK;
    WxT[i] = W_x[k * DM + d];
  }
  int j = i - DM * KK;
  if (j >= 0 && j < DTR * DM) {      // WdtT[r][d] = W_dt[d][r]
    int r = j / DM, d = j % DM;
    WdtT[j] = W_dt[d * DTR + r];
  }
}

// xz[row][k] = sum_d x[row][d] * W_x[k][d]
// 512-thread block: 8 waves = 4 row-pairs x 2 d-halves; LDS reduce across halves.
__global__ __launch_bounds__(512) void k_xz(const float* __restrict__ x,
                                            const float* __restrict__ WxT,
                                            float* __restrict__ xz) {
  __shared__ float red[4][2][64];
  int k = threadIdx.x & 63;
  int wv = threadIdx.x >> 6;   // 0..7
  int rp = wv & 3;             // row pair
  int dh = wv >> 2;            // d half
  int row0 = blockIdx.x * 8 + rp * 2;
  const float* xr0 = x + (size_t)row0 * DM + dh * (DM / 2);
  const float* xr1 = xr0 + DM;
  const float* Wp = WxT + (size_t)dh * (DM / 2) * KK;
  float acc0 = 0.f, acc1 = 0.f;
  for (int d = 0; d < DM / 2; d += 8) {
    float4 u0 = *(const float4*)(xr0 + d);
    float4 u1 = *(const float4*)(xr0 + d + 4);
    float4 v0 = *(const float4*)(xr1 + d);
    float4 v1 = *(const float4*)(xr1 + d + 4);
    float w0 = Wp[(d + 0) * KK + k];
    float w1 = Wp[(d + 1) * KK + k];
    float w2 = Wp[(d + 2) * KK + k];
    float w3 = Wp[(d + 3) * KK + k];
    float w4 = Wp[(d + 4) * KK + k];
    float w5 = Wp[(d + 5) * KK + k];
    float w6 = Wp[(d + 6) * KK + k];
    float w7 = Wp[(d + 7) * KK + k];
    acc0 = fmaf(u0.x, w0, acc0); acc1 = fmaf(v0.x, w0, acc1);
    acc0 = fmaf(u0.y, w1, acc0); acc1 = fmaf(v0.y, w1, acc1);
    acc0 = fmaf(u0.z, w2, acc0); acc1 = fmaf(v0.z, w2, acc1);
    acc0 = fmaf(u0.w, w3, acc0); acc1 = fmaf(v0.w, w3, acc1);
    acc0 = fmaf(u1.x, w4, acc0); acc1 = fmaf(v1.x, w4, acc1);
    acc0 = fmaf(u1.y, w5, acc0); acc1 = fmaf(v1.y, w5, acc1);
    acc0 = fmaf(u1.z, w6, acc0); acc1 = fmaf(v1.z, w6, acc1);
    acc0 = fmaf(u1.w, w7, acc0); acc1 = fmaf(v1.w, w7, acc1);
  }
  if (dh == 1) {
    red[rp][0][k] = acc0;
    red[rp][1][k] = acc1;
  }
  __syncthreads();
  if (dh == 0) {
    acc0 += red[rp][0][k];
    acc1 += red[rp][1][k];
    xz[(size_t)row0 * KK + k] = acc0;
    xz[(size_t)(row0 + 1) * KK + k] = acc1;
  }
}

// dt[row][d] = clip(softplus(sum_r dt_raw[row][r]*W_dt[d][r] + b_dt[d]), 1e-4, 10)
// [l][d] layout, coalesced stores.
__global__ __launch_bounds__(256) void k_dt(const float* __restrict__ xz,
                                            const float* __restrict__ WdtT,
                                            const float* __restrict__ b_dt,
                                            float* __restrict__ dtw) {
  int d = (blockIdx.x & 1) * 256 + threadIdx.x;
  int row0 = (blockIdx.x >> 1) * 8;
  float acc[8] = {0, 0, 0, 0, 0, 0, 0, 0};
  for (int r = 0; r < DTR; ++r) {
    float w = WdtT[r * DM + d];
#pragma unroll
    for (int i = 0; i < 8; ++i)
      acc[i] += xz[(row0 + i) * KK + r] * w;
  }
  float bd = b_dt[d];
#pragma unroll
  for (int i = 0; i < 8; ++i) {
    float v = acc[i] + bd;
    float sp = v > 15.f ? v : __logf(1.f + __expf(v));
    sp = fminf(fmaxf(sp, 1e-4f), 10.f);
    dtw[(size_t)(row0 + i) * DM + d] = sp;
  }
}

// Pass 1: per-chunk (prod A_bar, local h). 4 states/thread.
// dt/x preloaded to registers (breaks the load->recurrence latency chain);
// B quads preloaded in two batches of 8.
__global__ __launch_bounds__(256) void k_scan1(const float* __restrict__ x,
                                               const float* __restrict__ xz,
                                               const float* __restrict__ dtw,
                                               const float* __restrict__ A_log,
                                               float* __restrict__ Pb,
                                               float* __restrict__ Hb) {
  int c = blockIdx.x;
  int b = blockIdx.y >> 3;
  int dblk = blockIdx.y & 7;
  int tid = threadIdx.x;
  int s4 = tid & 3, dloc = tid >> 2;
  int d = dblk * 64 + dloc;

  int l0 = c * CL;
  const float* dt_p = dtw + ((size_t)b * LL + l0) * DM + d;
  const float* x_p  = x   + ((size_t)b * LL + l0) * DM + d;
  const float* B_p  = xz  + ((size_t)b * LL + l0) * KK + DTR + s4 * 4;

  float dtv[CL], xv[CL];
#pragma unroll
  for (int l = 0; l < CL; ++l) dtv[l] = dt_p[(size_t)l * DM];
#pragma unroll
  for (int l = 0; l < CL; ++l) xv[l] = x_p[(size_t)l * DM];

  float4 al = *(const float4*)(A_log + d * DS + s4 * 4);
  float A0 = fminf(-__expf(al.x), -1e-4f);
  float A1 = fminf(-__expf(al.y), -1e-4f);
  float A2 = fminf(-__expf(al.z), -1e-4f);
  float A3 = fminf(-__expf(al.w), -1e-4f);

  float P0 = 1.f, P1 = 1.f, P2 = 1.f, P3 = 1.f;
  float h0 = 0.f, h1 = 0.f, h2 = 0.f, h3 = 0.f;

  float4 Bq[8];
#pragma unroll
  for (int half = 0; half < 2; ++half) {
#pragma unroll
    for (int i = 0; i < 8; ++i)
      Bq[i] = *(const float4*)(B_p + (size_t)(half * 8 + i) * KK);
#pragma unroll
    for (int i = 0; i < 8; ++i) {
      int l = half * 8 + i;
      float u = dtv[l] * xv[l];
      float a0 = fminf(__expf(dtv[l] * A0), 1.f);
      float a1 = fminf(__expf(dtv[l] * A1), 1.f);
      float a2 = fminf(__expf(dtv[l] * A2), 1.f);
      float a3 = fminf(__expf(dtv[l] * A3), 1.f);
      h0 = fmaf(a0, h0, u * Bq[i].x); P0 *= a0;
      h1 = fmaf(a1, h1, u * Bq[i].y); P1 *= a1;
      h2 = fmaf(a2, h2, u * Bq[i].z); P2 *= a2;
      h3 = fmaf(a3, h3, u * Bq[i].w); P3 *= a3;
    }
  }
  int chain0 = (b * DM + d) * DS + s4 * 4;
  *(float4*)(Pb + (size_t)c * CHAINS + chain0) = make_float4(P0, P1, P2, P3);
  *(float4*)(Hb + (size_t)c * CHAINS + chain0) = make_float4(h0, h1, h2, h3);
}

// Carry scan over chunks. PURE: reads Pb/Hb, writes Cb.
__global__ __launch_bounds__(256) void k_mid(const float* __restrict__ Pb,
                                             const float* __restrict__ Hb,
                                             float* __restrict__ Cb) {
  int chain = blockIdx.x * 256 + threadIdx.x;
  float h = 0.f;
#pragma unroll 16
  for (int c = 0; c < NC; ++c) {
    float Pv = Pb[(size_t)c * CHAINS + chain];
    float Hv = Hb[(size_t)c * CHAINS + chain];
    Cb[(size_t)c * CHAINS + chain] = h;
    h = fmaf(Pv, h, Hv);
  }
}

// Pass 2: carry-in + local scan + y. Same preload scheme as pass 1, plus C.
__global__ __launch_bounds__(256) void k_scan2(const float* __restrict__ x,
                                               const float* __restrict__ xz,
                                               const float* __restrict__ dtw,
                                               const float* __restrict__ A_log,
                                               const float* __restrict__ Dv,
                                               const float* __restrict__ Cb,
                                               float* __restrict__ y) {
  int c = blockIdx.x;
  int b = blockIdx.y >> 3;
  int dblk = blockIdx.y & 7;
  int tid = threadIdx.x;
  int s4 = tid & 3, dloc = tid >> 2;
  int d = dblk * 64 + dloc;

  int l0 = c * CL;
  const float* dt_p = dtw + ((size_t)b * LL + l0) * DM + d;
  const float* x_p  = x   + ((size_t)b * LL + l0) * DM + d;
  const float* B_p  = xz  + ((size_t)b * LL + l0) * KK + DTR + s4 * 4;
  const float* C_p  = B_p + DS;
  float* y_p = y + ((size_t)b * LL + l0) * DM + d;

  float dtv[CL], xv[CL];
#pragma unroll
  for (int l = 0; l < CL; ++l) dtv[l] = dt_p[(size_t)l * DM];
#pragma unroll
  for (int l = 0; l < CL; ++l) xv[l] = x_p[(size_t)l * DM];

  int chain0 = (b * DM + d) * DS + s4 * 4;
  float4 hc = *(const float4*)(Cb + (size_t)c * CHAINS + chain0);
  float h0 = hc.x, h1 = hc.y, h2 = hc.z, h3 = hc.w;

  float4 al = *(const float4*)(A_log + d * DS + s4 * 4);
  float A0 = fminf(-__expf(al.x), -1e-4f);
  float A1 = fminf(-__expf(al.y), -1e-4f);
  float A2 = fminf(-__expf(al.z), -1e-4f);
  float A3 = fminf(-__expf(al.w), -1e-4f);
  float Dd = Dv[d];

  float4 Bq[8], Cq[8];
#pragma unroll
  for (int half = 0; half < 2; ++half) {
#pragma unroll
    for (int i = 0; i < 8; ++i) {
      Bq[i] = *(const float4*)(B_p + (size_t)(half * 8 + i) * KK);
      Cq[i] = *(const float4*)(C_p + (size_t)(half * 8 + i) * KK);
    }
#pragma unroll
    for (int i = 0; i < 8; ++i) {
      int l = half * 8 + i;
      float u = dtv[l] * xv[l];
      float a0 = fminf(__expf(dtv[l] * A0), 1.f);
      float a1 = fminf(__expf(dtv[l] * A1), 1.f);
      float a2 = fminf(__expf(dtv[l] * A2), 1.f);
      float a3 = fminf(__expf(dtv[l] * A3), 1.f);
      h0 = fmaf(a0, h0, u * Bq[i].x);
      h1 = fmaf(a1, h1, u * Bq[i].y);
      h2 = fmaf(a2, h2, u * Bq[i].z);
      h3 = fmaf(a3, h3, u * Bq[i].w);
      float p = h0 * Cq[i].x;
      p = fmaf(h1, Cq[i].y, p);
      p = fmaf(h2, Cq[i].z, p);
      p = fmaf(h3, Cq[i].w, p);
      p += __shfl_xor(p, 1);
      p += __shfl_xor(p, 2);
      if (s4 == 0)
        y_p[(size_t)l * DM] = fmaf(xv[l], Dd, p);
    }
  }
}

extern "C" void kernel_launch(void* const* d_in, const int* in_sizes, int n_in,
                              void* d_out, int out_size, void* d_ws, size_t ws_size,
                              hipStream_t stream) {
  const float* x     = (const float*)d_in[0];
  const float* W_x   = (const float*)d_in[1];
  const float* W_dt  = (const float*)d_in[2];
  const float* b_dt  = (const float*)d_in[3];
  const float* A_log = (const float*)d_in[4];
  const float* Dv    = (const float*)d_in[5];
  float* y = (float*)d_out;

  float* ws   = (float*)d_ws;
  float* WxT  = ws + OFF_WXT;
  float* WdtT = ws + OFF_WDTT;
  float* xz   = ws + OFF_XZ;
  float* dtw  = ws + OFF_DT;
  float* Pb   = ws + OFF_P;
  float* Hb   = ws + OFF_H;
  float* Cb   = ws + OFF_C;

  k_prep<<<192, 256, 0, stream>>>(W_x, W_dt, WxT, WdtT);
  k_xz<<<NROWS / 8, 512, 0, stream>>>(x, WxT, xz);
  k_dt<<<(NROWS / 8) * 2, 256, 0, stream>>>(xz, WdtT, b_dt, dtw);
  dim3 g(NC, BB * (DM / 64));
  k_scan1<<<g, 256, 0, stream>>>(x, xz, dtw, A_log, Pb, Hb);
  k_mid<<<CHAINS / 256, 256, 0, stream>>>(Pb, Hb, Cb);
  k_scan2<<<g, 256, 0, stream>>>(x, xz, dtw, A_log, Dv, Cb, y);
}

// Round 7
// 78.037 us; speedup vs baseline: 1.4101x; 1.3990x over previous
//
#include <hip/hip_runtime.h>
#include <math.h>

#define BB 2
#define LL 2048
#define DM 512
#define DS 16
#define DTR 32
#define KK 64          // DTR + 2*DS
#define NC 128         // chunks
#define CL 16          // LL / NC
#define NROWS (BB * LL)
#define CHAINS (BB * DM * DS)   // 16384

// ws layout (floats) — ~35 MB, ws is ~268 MB
#define OFF_WXT  0                        // 512*64    = 32768
#define OFF_WDTT (OFF_WXT + DM * KK)      // 32*512    = 16384
#define OFF_XZ   (OFF_WDTT + DTR * DM)    // 4096*64   = 262144
#define OFF_DT   (OFF_XZ + NROWS * KK)    // 4096*512  = 2097152
#define OFF_P    (OFF_DT + NROWS * DM)    // 128*16384 = 2097152
#define OFF_H    (OFF_P + NC * CHAINS)    // 128*16384 = 2097152
#define OFF_C    (OFF_H + NC * CHAINS)    // 128*16384 = 2097152

__global__ __launch_bounds__(256) void k_prep(const float* __restrict__ W_x,
                                              const float* __restrict__ W_dt,
                                              float* __restrict__ WxT,
                                              float* __restrict__ WdtT) {
  int i = blockIdx.x * 256 + threadIdx.x;
  if (i < DM * KK) {                 // WxT[d][k] = W_x[k][d]
    int d = i / KK, k = i % KK;
    WxT[i] = W_x[k * DM + d];
  }
  int j = i - DM * KK;
  if (j >= 0 && j < DTR * DM) {      // WdtT[r][d] = W_dt[d][r]
    int r = j / DM, d = j % DM;
    WdtT[j] = W_dt[d * DTR + r];
  }
}

// Fused front-end: xz GEMM phase + dt phase (per-block pipeline, no global sync).
// Phase 1 (as round-4 k_xz): 8 waves = 4 row-pairs x 2 d-halves, LDS reduce.
// Phase 2: dt_raw (8x32) via LDS; 512 threads each compute one d for 8 rows.
__global__ __launch_bounds__(512) void k_fe(const float* __restrict__ x,
                                            const float* __restrict__ WxT,
                                            const float* __restrict__ WdtT,
                                            const float* __restrict__ b_dt,
                                            float* __restrict__ xz,
                                            float* __restrict__ dtw) {
  __shared__ float red[4][2][64];
  __shared__ float draw[8][32];
  int k = threadIdx.x & 63;
  int wv = threadIdx.x >> 6;   // 0..7
  int rp = wv & 3;             // row pair
  int dh = wv >> 2;            // d half
  int row0 = blockIdx.x * 8 + rp * 2;
  const float* xr0 = x + (size_t)row0 * DM + dh * (DM / 2);
  const float* xr1 = xr0 + DM;
  const float* Wp = WxT + (size_t)dh * (DM / 2) * KK;
  float acc0 = 0.f, acc1 = 0.f;
  for (int d = 0; d < DM / 2; d += 8) {
    float4 u0 = *(const float4*)(xr0 + d);
    float4 u1 = *(const float4*)(xr0 + d + 4);
    float4 v0 = *(const float4*)(xr1 + d);
    float4 v1 = *(const float4*)(xr1 + d + 4);
    float w0 = Wp[(d + 0) * KK + k];
    float w1 = Wp[(d + 1) * KK + k];
    float w2 = Wp[(d + 2) * KK + k];
    float w3 = Wp[(d + 3) * KK + k];
    float w4 = Wp[(d + 4) * KK + k];
    float w5 = Wp[(d + 5) * KK + k];
    float w6 = Wp[(d + 6) * KK + k];
    float w7 = Wp[(d + 7) * KK + k];
    acc0 = fmaf(u0.x, w0, acc0); acc1 = fmaf(v0.x, w0, acc1);
    acc0 = fmaf(u0.y, w1, acc0); acc1 = fmaf(v0.y, w1, acc1);
    acc0 = fmaf(u0.z, w2, acc0); acc1 = fmaf(v0.z, w2, acc1);
    acc0 = fmaf(u0.w, w3, acc0); acc1 = fmaf(v0.w, w3, acc1);
    acc0 = fmaf(u1.x, w4, acc0); acc1 = fmaf(v1.x, w4, acc1);
    acc0 = fmaf(u1.y, w5, acc0); acc1 = fmaf(v1.y, w5, acc1);
    acc0 = fmaf(u1.z, w6, acc0); acc1 = fmaf(v1.z, w6, acc1);
    acc0 = fmaf(u1.w, w7, acc0); acc1 = fmaf(v1.w, w7, acc1);
  }
  if (dh == 1) {
    red[rp][0][k] = acc0;
    red[rp][1][k] = acc1;
  }
  __syncthreads();
  if (dh == 0) {
    acc0 += red[rp][0][k];
    acc1 += red[rp][1][k];
    xz[(size_t)row0 * KK + k] = acc0;
    xz[(size_t)(row0 + 1) * KK + k] = acc1;
    if (k < DTR) {
      draw[rp * 2][k] = acc0;
      draw[rp * 2 + 1][k] = acc1;
    }
  }
  __syncthreads();
  // Phase 2: dt for this block's 8 rows; thread = one d.
  int d = threadIdx.x;   // 0..511
  float acc[8] = {0, 0, 0, 0, 0, 0, 0, 0};
  for (int r = 0; r < DTR; ++r) {
    float w = WdtT[r * DM + d];
#pragma unroll
    for (int i = 0; i < 8; ++i)
      acc[i] = fmaf(draw[i][r], w, acc[i]);
  }
  float bd = b_dt[d];
#pragma unroll
  for (int i = 0; i < 8; ++i) {
    float v = acc[i] + bd;
    float sp = v > 15.f ? v : __logf(1.f + __expf(v));
    sp = fminf(fmaxf(sp, 1e-4f), 10.f);
    dtw[(size_t)(blockIdx.x * 8 + i) * DM + d] = sp;
  }
}

// Pass 1: per-chunk (prod A_bar, local h). 4 states/thread. (round-4 form)
__global__ __launch_bounds__(256) void k_scan1(const float* __restrict__ x,
                                               const float* __restrict__ xz,
                                               const float* __restrict__ dtw,
                                               const float* __restrict__ A_log,
                                               float* __restrict__ Pb,
                                               float* __restrict__ Hb) {
  int c = blockIdx.x;
  int b = blockIdx.y >> 3;
  int dblk = blockIdx.y & 7;
  int tid = threadIdx.x;
  int s4 = tid & 3, dloc = tid >> 2;
  int d = dblk * 64 + dloc;

  float4 al = *(const float4*)(A_log + d * DS + s4 * 4);
  float A0 = fminf(-__expf(al.x), -1e-4f);
  float A1 = fminf(-__expf(al.y), -1e-4f);
  float A2 = fminf(-__expf(al.z), -1e-4f);
  float A3 = fminf(-__expf(al.w), -1e-4f);

  float P0 = 1.f, P1 = 1.f, P2 = 1.f, P3 = 1.f;
  float h0 = 0.f, h1 = 0.f, h2 = 0.f, h3 = 0.f;

  int l0 = c * CL;
  const float* dt_p = dtw + ((size_t)b * LL + l0) * DM + d;
  const float* x_p  = x   + ((size_t)b * LL + l0) * DM + d;
  const float* B_p  = xz  + ((size_t)b * LL + l0) * KK + DTR + s4 * 4;
#pragma unroll 4
  for (int l = 0; l < CL; ++l) {
    float dtv = dt_p[(size_t)l * DM];
    float xv  = x_p[(size_t)l * DM];
    float4 Bv = *(const float4*)(B_p + (size_t)l * KK);
    float dtx = dtv * xv;
    float a0 = fminf(__expf(dtv * A0), 1.f);
    float a1 = fminf(__expf(dtv * A1), 1.f);
    float a2 = fminf(__expf(dtv * A2), 1.f);
    float a3 = fminf(__expf(dtv * A3), 1.f);
    h0 = fmaf(a0, h0, dtx * Bv.x); P0 *= a0;
    h1 = fmaf(a1, h1, dtx * Bv.y); P1 *= a1;
    h2 = fmaf(a2, h2, dtx * Bv.z); P2 *= a2;
    h3 = fmaf(a3, h3, dtx * Bv.w); P3 *= a3;
  }
  int chain0 = (b * DM + d) * DS + s4 * 4;
  *(float4*)(Pb + (size_t)c * CHAINS + chain0) = make_float4(P0, P1, P2, P3);
  *(float4*)(Hb + (size_t)c * CHAINS + chain0) = make_float4(h0, h1, h2, h3);
}

// Carry scan over chunks. PURE: reads Pb/Hb, writes Cb.
// 64-thread blocks spread the 24 MB stream across all CUs.
__global__ __launch_bounds__(64) void k_mid(const float* __restrict__ Pb,
                                            const float* __restrict__ Hb,
                                            float* __restrict__ Cb) {
  int chain = blockIdx.x * 64 + threadIdx.x;
  float h = 0.f;
#pragma unroll 8
  for (int c = 0; c < NC; ++c) {
    float Pv = Pb[(size_t)c * CHAINS + chain];
    float Hv = Hb[(size_t)c * CHAINS + chain];
    Cb[(size_t)c * CHAINS + chain] = h;
    h = fmaf(Pv, h, Hv);
  }
}

// Pass 2: carry-in + local scan + y output. (round-4 form)
__global__ __launch_bounds__(256) void k_scan2(const float* __restrict__ x,
                                               const float* __restrict__ xz,
                                               const float* __restrict__ dtw,
                                               const float* __restrict__ A_log,
                                               const float* __restrict__ Dv,
                                               const float* __restrict__ Cb,
                                               float* __restrict__ y) {
  int c = blockIdx.x;
  int b = blockIdx.y >> 3;
  int dblk = blockIdx.y & 7;
  int tid = threadIdx.x;
  int s4 = tid & 3, dloc = tid >> 2;
  int d = dblk * 64 + dloc;

  int chain0 = (b * DM + d) * DS + s4 * 4;
  float4 hc = *(const float4*)(Cb + (size_t)c * CHAINS + chain0);
  float h0 = hc.x, h1 = hc.y, h2 = hc.z, h3 = hc.w;

  float4 al = *(const float4*)(A_log + d * DS + s4 * 4);
  float A0 = fminf(-__expf(al.x), -1e-4f);
  float A1 = fminf(-__expf(al.y), -1e-4f);
  float A2 = fminf(-__expf(al.z), -1e-4f);
  float A3 = fminf(-__expf(al.w), -1e-4f);
  float Dd = Dv[d];

  int l0 = c * CL;
  const float* dt_p = dtw + ((size_t)b * LL + l0) * DM + d;
  const float* x_p  = x   + ((size_t)b * LL + l0) * DM + d;
  const float* B_p  = xz  + ((size_t)b * LL + l0) * KK + DTR + s4 * 4;
  const float* C_p  = B_p + DS;
  float* y_p = y + ((size_t)b * LL + l0) * DM + d;
#pragma unroll 4
  for (int l = 0; l < CL; ++l) {
    float dtv = dt_p[(size_t)l * DM];
    float xv  = x_p[(size_t)l * DM];
    float4 Bv = *(const float4*)(B_p + (size_t)l * KK);
    float4 Cv = *(const float4*)(C_p + (size_t)l * KK);
    float dtx = dtv * xv;
    float a0 = fminf(__expf(dtv * A0), 1.f);
    float a1 = fminf(__expf(dtv * A1), 1.f);
    float a2 = fminf(__expf(dtv * A2), 1.f);
    float a3 = fminf(__expf(dtv * A3), 1.f);
    h0 = fmaf(a0, h0, dtx * Bv.x);
    h1 = fmaf(a1, h1, dtx * Bv.y);
    h2 = fmaf(a2, h2, dtx * Bv.z);
    h3 = fmaf(a3, h3, dtx * Bv.w);
    float p = h0 * Cv.x;
    p = fmaf(h1, Cv.y, p);
    p = fmaf(h2, Cv.z, p);
    p = fmaf(h3, Cv.w, p);
    p += __shfl_xor(p, 1);
    p += __shfl_xor(p, 2);
    if (s4 == 0)
      y_p[(size_t)l * DM] = fmaf(xv, Dd, p);
  }
}

extern "C" void kernel_launch(void* const* d_in, const int* in_sizes, int n_in,
                              void* d_out, int out_size, void* d_ws, size_t ws_size,
                              hipStream_t stream) {
  const float* x     = (const float*)d_in[0];
  const float* W_x   = (const float*)d_in[1];
  const float* W_dt  = (const float*)d_in[2];
  const float* b_dt  = (const float*)d_in[3];
  const float* A_log = (const float*)d_in[4];
  const float* Dv    = (const float*)d_in[5];
  float* y = (float*)d_out;

  float* ws   = (float*)d_ws;
  float* WxT  = ws + OFF_WXT;
  float* WdtT = ws + OFF_WDTT;
  float* xz   = ws + OFF_XZ;
  float* dtw  = ws + OFF_DT;
  float* Pb   = ws + OFF_P;
  float* Hb   = ws + OFF_H;
  float* Cb   = ws + OFF_C;

  k_prep<<<192, 256, 0, stream>>>(W_x, W_dt, WxT, WdtT);
  k_fe<<<NROWS / 8, 512, 0, stream>>>(x, WxT, WdtT, b_dt, xz, dtw);
  dim3 g(NC, BB * (DM / 64));
  k_scan1<<<g, 256, 0, stream>>>(x, xz, dtw, A_log, Pb, Hb);
  k_mid<<<CHAINS / 64, 64, 0, stream>>>(Pb, Hb, Cb);
  k_scan2<<<g, 256, 0, stream>>>(x, xz, dtw, A_log, Dv, Cb, y);
}